// Round 1
// baseline (1179.720 us; speedup 1.0000x reference)
//
#include <hip/hip_runtime.h>
#include <hip/hip_bf16.h>

#define Hd 1024
#define Bdim 2
#define Sd 2048
#define BSd 4096
#define Vd 32000
#define EPSf 1e-5f
#define CH 64
#define NCH 32

typedef __attribute__((ext_vector_type(8))) short short8;
typedef __attribute__((ext_vector_type(4))) float f32x4;
typedef __attribute__((ext_vector_type(4))) unsigned short us4;

__device__ __forceinline__ unsigned short f2bf(float f) {
  union { float f; unsigned int u; } v; v.f = f;
  return (unsigned short)((v.u + 0x7fffu + ((v.u >> 16) & 1u)) >> 16);
}

// ---------------- convert fp32 -> bf16 (vectorized x4) ----------------
__global__ void k_cvt(const float* __restrict__ in, unsigned short* __restrict__ out, int n4) {
  int i = blockIdx.x * 256 + threadIdx.x;
  if (i >= n4) return;
  f32x4 v = *(const f32x4*)(in + (size_t)i * 4);
  us4 o;
  o[0] = f2bf(v[0]); o[1] = f2bf(v[1]); o[2] = f2bf(v[2]); o[3] = f2bf(v[3]);
  *(us4*)(out + (size_t)i * 4) = o;
}

// ---------------- embedding gather -> fp32 + bf16 ----------------
__global__ void k_embed(const int* __restrict__ x, const float* __restrict__ E,
                        float* __restrict__ emb, unsigned short* __restrict__ embbf) {
  int row = blockIdx.x, t = threadIdx.x;
  int id = x[row];
  f32x4 v = *(const f32x4*)(E + (size_t)id * Hd + t * 4);
  *(f32x4*)(emb + (size_t)row * Hd + t * 4) = v;
  us4 o;
  o[0] = f2bf(v[0]); o[1] = f2bf(v[1]); o[2] = f2bf(v[2]); o[3] = f2bf(v[3]);
  *(us4*)(embbf + (size_t)row * Hd + t * 4) = o;
}

// ---------------- bf16 NT GEMM: C[M,N] = A[M,K] * B[N,K]^T (+bias) ----------------
// 128x128 tile, BK=32, 256 threads = 4 waves (2x2), each wave 64x64 = 4x4 frags.
// LDS rows padded to 40 elems (80B) -> ds_read_b128 start banks spread 8-way (free 2-way).
template<int BF16_OUT>
__launch_bounds__(256)
__global__ void gemm_nt(const unsigned short* __restrict__ A,
                        const unsigned short* __restrict__ Bw,
                        const float* __restrict__ bias,
                        void* __restrict__ Cv,
                        int N, int K, int ldc, int coff)
{
  __shared__ __align__(16) unsigned short As[128 * 40];
  __shared__ __align__(16) unsigned short Bs[128 * 40];
  int tid = threadIdx.x;
  int row0 = blockIdx.y * 128, col0 = blockIdx.x * 128;
  int wave = tid >> 6, lane = tid & 63;
  int wr = (wave >> 1) * 64, wc = (wave & 1) * 64;
  int lr = lane & 15, lk = (lane >> 4) * 8;
  f32x4 acc[4][4] = {};
  for (int k0 = 0; k0 < K; k0 += 32) {
    #pragma unroll
    for (int it = 0; it < 2; ++it) {
      int ch = tid + it * 256;
      int r = ch >> 2, c8 = (ch & 3) * 8;
      short8 av = *(const short8*)(A + (size_t)(row0 + r) * K + k0 + c8);
      *(short8*)(As + r * 40 + c8) = av;
      int brow = col0 + r;
      short8 bv = (short8)0;
      if (brow < N) bv = *(const short8*)(Bw + (size_t)brow * K + k0 + c8);
      *(short8*)(Bs + r * 40 + c8) = bv;
    }
    __syncthreads();
    short8 afr[4], bfr[4];
    #pragma unroll
    for (int m = 0; m < 4; ++m)
      afr[m] = *(const short8*)(As + (wr + m * 16 + lr) * 40 + lk);
    #pragma unroll
    for (int n = 0; n < 4; ++n)
      bfr[n] = *(const short8*)(Bs + (wc + n * 16 + lr) * 40 + lk);
    #pragma unroll
    for (int m = 0; m < 4; ++m)
      #pragma unroll
      for (int n = 0; n < 4; ++n)
        acc[m][n] = __builtin_amdgcn_mfma_f32_16x16x32_bf16(afr[m], bfr[n], acc[m][n], 0, 0, 0);
    __syncthreads();
  }
  int rb = (lane >> 4) * 4;
  #pragma unroll
  for (int m = 0; m < 4; ++m) {
    #pragma unroll
    for (int n = 0; n < 4; ++n) {
      int gcol = col0 + wc + n * 16 + lr;
      if (gcol >= N) continue;
      float bv = bias ? bias[gcol] : 0.f;
      #pragma unroll
      for (int j = 0; j < 4; ++j) {
        int grow = row0 + wr + m * 16 + rb + j;
        float val = acc[m][n][j] + bv;
        if (BF16_OUT)
          ((unsigned short*)Cv)[(size_t)grow * ldc + coff + gcol] = f2bf(val);
        else
          ((float*)Cv)[(size_t)grow * ldc + coff + gcol] = val;
      }
    }
  }
}

// ---------------- u = sigmoid(gz) * bx ----------------
__global__ void k_gate_u(const float* __restrict__ gz, const float* __restrict__ bx,
                         float* __restrict__ u, int n) {
  int i = blockIdx.x * 256 + threadIdx.x;
  if (i >= n) return;
  float s = 1.f / (1.f + expf(-gz[i]));
  u[i] = s * bx[i];
}

// ---------------- chunked diagonal scan ----------------
// phase A: local scans of CH steps per (b, chunk, n); coalesced over n
__global__ void k_scanA(const float* __restrict__ u, const float* __restrict__ Alog,
                        float* __restrict__ st, float* __restrict__ carry, int N) {
  int b = blockIdx.x / NCH, c = blockIdx.x % NCH;
  int n = threadIdx.x;
  float a = expf(Alog[n]);
  float s = 0.f;
  size_t base = ((size_t)b * Sd + (size_t)c * CH) * N + n;
  for (int t = 0; t < CH; ++t) {
    s = a * s + u[base + (size_t)t * N];
    st[base + (size_t)t * N] = s;
  }
  carry[(b * NCH + c) * N + n] = s;
}

// phase B: scan carries across chunks (tiny)
__global__ void k_scanB(const float* __restrict__ carry, const float* __restrict__ Alog,
                        float* __restrict__ cin, int N) {
  int i = threadIdx.x;
  if (i >= Bdim * N) return;
  int b = i / N, n = i % N;
  float aC = expf((float)CH * Alog[n]);
  float s = 0.f;
  for (int c = 0; c < NCH; ++c) {
    cin[(b * NCH + c) * N + n] = s;
    s = aC * s + carry[(b * NCH + c) * N + n];
  }
}

// phase C: states = local + A^(t+1)*carry_in, emit bf16
__global__ void k_scanC(const float* __restrict__ st, const float* __restrict__ cin,
                        const float* __restrict__ Alog, unsigned short* __restrict__ stbf, int N) {
  int row = blockIdx.x;  // b*Sd + s
  int n = threadIdx.x;
  int b = row / Sd, sg = row % Sd;
  int c = sg / CH, t = sg % CH;
  float cv = cin[(b * NCH + c) * N + n];
  float val = st[(size_t)row * N + n] + expf((float)(t + 1) * Alog[n]) * cv;
  stbf[(size_t)row * N + n] = f2bf(val);
}

// ---------------- fused LN: z = LN(y + coef*emb)*g + be -> bf16 ----------------
// coef = D[h]+1 for layers (y holds states@Wc^T), coef = 1 for final (D==nullptr)
__global__ void k_ln(const float* __restrict__ y, const float* __restrict__ emb,
                     const float* __restrict__ D, const float* __restrict__ g,
                     const float* __restrict__ be, unsigned short* __restrict__ out) {
  int row = blockIdx.x, t = threadIdx.x;
  f32x4 yv = *(const f32x4*)(y + (size_t)row * Hd + t * 4);
  f32x4 ev = *(const f32x4*)(emb + (size_t)row * Hd + t * 4);
  float vals[4];
  float sum = 0.f, sq = 0.f;
  #pragma unroll
  for (int j = 0; j < 4; ++j) {
    float coef = D ? (D[t * 4 + j] + 1.f) : 1.f;
    float v = yv[j] + coef * ev[j];
    vals[j] = v; sum += v; sq += v * v;
  }
  #pragma unroll
  for (int o = 32; o >= 1; o >>= 1) {
    sum += __shfl_xor(sum, o);
    sq += __shfl_xor(sq, o);
  }
  __shared__ float red[2][4];
  int w = t >> 6, lane = t & 63;
  if (lane == 0) { red[0][w] = sum; red[1][w] = sq; }
  __syncthreads();
  sum = red[0][0] + red[0][1] + red[0][2] + red[0][3];
  sq  = red[1][0] + red[1][1] + red[1][2] + red[1][3];
  float mean = sum * (1.f / Hd);
  float var = sq * (1.f / Hd) - mean * mean;
  float rs = rsqrtf(var + EPSf);
  us4 o4;
  #pragma unroll
  for (int j = 0; j < 4; ++j) {
    float z = (vals[j] - mean) * rs * g[t * 4 + j] + be[t * 4 + j];
    o4[j] = f2bf(z);
  }
  *(us4*)(out + (size_t)row * Hd + t * 4) = o4;
}

extern "C" void kernel_launch(void* const* d_in, const int* in_sizes, int n_in,
                              void* d_out, int out_size, void* d_ws, size_t ws_size,
                              hipStream_t stream) {
  (void)in_sizes; (void)n_in; (void)out_size; (void)ws_size;
  const int* x = (const int*)d_in[0];
  const float* E = (const float*)d_in[1];
  const float* Wf_ = (const float*)d_in[32];
  const float* bfb = (const float*)d_in[33];
  const float* gfp = (const float*)d_in[34];
  const float* bef = (const float*)d_in[35];
  const float* Wh_ = (const float*)d_in[36];
  const float* bh = (const float*)d_in[37];
  static const int sd[3] = {64, 128, 256};

  char* wsb = (char*)d_ws;
  size_t off = 0;
  auto alloc = [&](size_t bytes) -> void* {
    void* p = wsb + off;
    off += (bytes + 255) & ~(size_t)255;
    return p;
  };
  float* emb            = (float*)alloc((size_t)BSd * Hd * 4);
  unsigned short* embbf = (unsigned short*)alloc((size_t)BSd * Hd * 2);
  unsigned short* wgbf  = (unsigned short*)alloc((size_t)448 * Hd * 2);
  unsigned short* wbbf  = (unsigned short*)alloc((size_t)448 * Hd * 2);
  unsigned short* wcbf  = (unsigned short*)alloc((size_t)448 * Hd * 2);
  unsigned short* wobf  = (unsigned short*)alloc((size_t)3 * Hd * Hd * 2);
  unsigned short* wfbf  = (unsigned short*)alloc((size_t)3 * Hd * Hd * 2);
  unsigned short* whbf  = (unsigned short*)alloc((size_t)Vd * Hd * 2);
  float* gz             = (float*)alloc((size_t)BSd * 256 * 4);
  float* bx             = (float*)alloc((size_t)BSd * 256 * 4);
  float* u              = (float*)alloc((size_t)BSd * 256 * 4);
  float* stl            = (float*)alloc((size_t)BSd * 256 * 4);
  unsigned short* stbf  = (unsigned short*)alloc((size_t)BSd * 256 * 2);
  float* carry          = (float*)alloc((size_t)Bdim * NCH * 256 * 4);
  float* cin            = (float*)alloc((size_t)Bdim * NCH * 256 * 4);
  float* ybuf           = (float*)alloc((size_t)BSd * Hd * 4);
  unsigned short* zbf   = (unsigned short*)alloc((size_t)BSd * Hd * 2);
  unsigned short* combbf= (unsigned short*)alloc((size_t)BSd * 3 * Hd * 2);

  k_embed<<<BSd, 256, 0, stream>>>(x, E, emb, embbf);

  const int owg[3] = {0, 64 * Hd, 192 * Hd};
  for (int i = 0; i < 3; ++i) {
    int n4 = sd[i] * Hd / 4;
    k_cvt<<<(n4 + 255) / 256, 256, 0, stream>>>((const float*)d_in[2 + 10 * i + 4], wgbf + owg[i], n4);
    k_cvt<<<(n4 + 255) / 256, 256, 0, stream>>>((const float*)d_in[2 + 10 * i + 1], wbbf + owg[i], n4);
    k_cvt<<<(n4 + 255) / 256, 256, 0, stream>>>((const float*)d_in[2 + 10 * i + 2], wcbf + owg[i], n4);
    int m4 = Hd * Hd / 4;
    k_cvt<<<(m4 + 255) / 256, 256, 0, stream>>>((const float*)d_in[2 + 10 * i + 6], wobf + (size_t)i * Hd * Hd, m4);
  }
  {
    int n4 = 3 * Hd * Hd / 4;
    k_cvt<<<(n4 + 255) / 256, 256, 0, stream>>>(Wf_, wfbf, n4);
  }
  {
    int n4 = Vd * Hd / 4;
    k_cvt<<<(n4 + 255) / 256, 256, 0, stream>>>(Wh_, whbf, n4);
  }

  for (int i = 0; i < 3; ++i) {
    int N = sd[i];
    const float* Alog = (const float*)d_in[2 + 10 * i + 0];
    const float* Dv   = (const float*)d_in[2 + 10 * i + 3];
    const float* bg   = (const float*)d_in[2 + 10 * i + 5];
    const float* bo   = (const float*)d_in[2 + 10 * i + 7];
    const float* gg   = (const float*)d_in[2 + 10 * i + 8];
    const float* be   = (const float*)d_in[2 + 10 * i + 9];

    dim3 gsmall((N + 127) / 128, BSd / 128);
    gemm_nt<0><<<gsmall, 256, 0, stream>>>(embbf, wgbf + owg[i], bg, gz, N, Hd, N, 0);
    gemm_nt<0><<<gsmall, 256, 0, stream>>>(embbf, wbbf + owg[i], nullptr, bx, N, Hd, N, 0);
    int tot = BSd * N;
    k_gate_u<<<(tot + 255) / 256, 256, 0, stream>>>(gz, bx, u, tot);
    k_scanA<<<Bdim * NCH, N, 0, stream>>>(u, Alog, stl, carry, N);
    k_scanB<<<1, 512, 0, stream>>>(carry, Alog, cin, N);
    k_scanC<<<BSd, N, 0, stream>>>(stl, cin, Alog, stbf, N);

    dim3 gy(Hd / 128, BSd / 128);
    gemm_nt<0><<<gy, 256, 0, stream>>>(stbf, wcbf + owg[i], nullptr, ybuf, Hd, N, Hd, 0);
    k_ln<<<BSd, 256, 0, stream>>>(ybuf, emb, Dv, gg, be, zbf);
    gemm_nt<1><<<gy, 256, 0, stream>>>(zbf, wobf + (size_t)i * Hd * Hd, bo, combbf, Hd, Hd, 3 * Hd, i * Hd);
  }

  dim3 gfgrid(Hd / 128, BSd / 128);
  gemm_nt<0><<<gfgrid, 256, 0, stream>>>(combbf, wfbf, bfb, ybuf, Hd, 3 * Hd, Hd, 0);
  k_ln<<<BSd, 256, 0, stream>>>(ybuf, emb, nullptr, gfp, bef, zbf);

  dim3 gh(Vd / 128, BSd / 128);
  gemm_nt<0><<<gh, 256, 0, stream>>>(zbf, whbf, bh, (float*)d_out, Vd, Hd, Vd, 0);
}

// Round 3
// 1111.835 us; speedup vs baseline: 1.0611x; 1.0611x over previous
//
#include <hip/hip_runtime.h>
#include <hip/hip_bf16.h>

#define Hd 1024
#define Bdim 2
#define Sd 2048
#define BSd 4096
#define Vd 32000
#define EPSf 1e-5f
#define CH 16
#define NCH 128

typedef __attribute__((ext_vector_type(8))) short short8;
typedef __attribute__((ext_vector_type(4))) float f32x4;
typedef __attribute__((ext_vector_type(4))) unsigned short us4;

__device__ __forceinline__ unsigned short f2bf(float f) {
  union { float f; unsigned int u; } v; v.f = f;
  return (unsigned short)((v.u + 0x7fffu + ((v.u >> 16) & 1u)) >> 16);
}

typedef __attribute__((address_space(1))) const void gvoid_t;
typedef __attribute__((address_space(3))) void svoid_t;
__device__ __forceinline__ void gl_lds16(const void* g, void* s) {
  __builtin_amdgcn_global_load_lds((gvoid_t*)g, (svoid_t*)s, 16, 0, 0);
}

// ---------------- convert fp32 -> bf16 (vectorized x4) ----------------
__global__ void k_cvt(const float* __restrict__ in, unsigned short* __restrict__ out, int n4) {
  int i = blockIdx.x * 256 + threadIdx.x;
  if (i >= n4) return;
  f32x4 v = *(const f32x4*)(in + (size_t)i * 4);
  us4 o;
  o[0] = f2bf(v[0]); o[1] = f2bf(v[1]); o[2] = f2bf(v[2]); o[3] = f2bf(v[3]);
  *(us4*)(out + (size_t)i * 4) = o;
}

// ---------------- embedding gather -> fp32 + bf16 ----------------
__global__ void k_embed(const int* __restrict__ x, const float* __restrict__ E,
                        float* __restrict__ emb, unsigned short* __restrict__ embbf) {
  int row = blockIdx.x, t = threadIdx.x;
  int id = x[row];
  f32x4 v = *(const f32x4*)(E + (size_t)id * Hd + t * 4);
  *(f32x4*)(emb + (size_t)row * Hd + t * 4) = v;
  us4 o;
  o[0] = f2bf(v[0]); o[1] = f2bf(v[1]); o[2] = f2bf(v[2]); o[3] = f2bf(v[3]);
  *(us4*)(embbf + (size_t)row * Hd + t * 4) = o;
}

// ---------------- bf16 NT GEMM: C[M,N] = A[M,K] * B[N,K]^T (+bias) ----------------
// m97 structure: 128x128 tile, BK=64, linear LDS, global_load_lds width=16,
// 2-barrier loop, 4 waves (2x2), 4x4 frags/wave of mfma_f32_16x16x32_bf16.
// 1-D grid, bijective XCD remap (m204) + N-panel-major order (B-panel L2-hot).
template<int BF16_OUT>
__launch_bounds__(256)
__global__ void gemm_nt(const unsigned short* __restrict__ A,
                        const unsigned short* __restrict__ Bw,
                        const float* __restrict__ bias,
                        void* __restrict__ Cv,
                        int N, int K, int ldc, int coff, int tm)
{
  __shared__ __align__(16) unsigned short As[128 * 64];
  __shared__ __align__(16) unsigned short Bs[128 * 64];
  int T = gridDim.x;
  int orig = blockIdx.x;
  int q = T >> 3, r = T & 7;
  int xc = orig & 7, sdv = orig >> 3;
  int wgid = (xc < r ? xc * (q + 1) : r * (q + 1) + (xc - r) * q) + sdv;
  int n_t = wgid / tm, m_t = wgid % tm;
  int row0 = m_t * 128, col0 = n_t * 128;

  int tid = threadIdx.x;
  int wave = tid >> 6, lane = tid & 63;
  int wr = (wave >> 1) * 64, wc = (wave & 1) * 64;
  int lr = lane & 15, lkb = (lane >> 4) * 8;
  // staging coords: issue blk covers rows blk*8..blk*8+7, lane l -> row blk*8 + l/8, col (l&7)*8
  int srow = lane >> 3;
  int scol = (lane & 7) * 8;

  f32x4 acc[4][4] = {};
  for (int k0 = 0; k0 < K; k0 += 64) {
    #pragma unroll
    for (int qq = 0; qq < 4; ++qq) {
      int blk = wave * 4 + qq;
      int arow = row0 + blk * 8 + srow;
      gl_lds16(A + (size_t)arow * K + k0 + scol, As + blk * 512);
      int brow = col0 + blk * 8 + srow;
      if (brow >= N) brow = N - 1;  // clamp: stay in-bounds; results masked at store
      gl_lds16(Bw + (size_t)brow * K + k0 + scol, Bs + blk * 512);
    }
    __syncthreads();
    #pragma unroll
    for (int kk = 0; kk < 2; ++kk) {
      short8 afr[4], bfr[4];
      #pragma unroll
      for (int m = 0; m < 4; ++m)
        afr[m] = *(const short8*)(As + (wr + m * 16 + lr) * 64 + kk * 32 + lkb);
      #pragma unroll
      for (int n = 0; n < 4; ++n)
        bfr[n] = *(const short8*)(Bs + (wc + n * 16 + lr) * 64 + kk * 32 + lkb);
      #pragma unroll
      for (int m = 0; m < 4; ++m)
        #pragma unroll
        for (int n = 0; n < 4; ++n)
          acc[m][n] = __builtin_amdgcn_mfma_f32_16x16x32_bf16(afr[m], bfr[n], acc[m][n], 0, 0, 0);
    }
    __syncthreads();
  }
  int rb = (lane >> 4) * 4;
  #pragma unroll
  for (int m = 0; m < 4; ++m) {
    #pragma unroll
    for (int n = 0; n < 4; ++n) {
      int gcol = col0 + wc + n * 16 + lr;
      if (gcol >= N) continue;
      float bv = bias ? bias[gcol] : 0.f;
      #pragma unroll
      for (int j = 0; j < 4; ++j) {
        int grow = row0 + wr + m * 16 + rb + j;
        float val = acc[m][n][j] + bv;
        if (BF16_OUT)
          ((unsigned short*)Cv)[(size_t)grow * ldc + coff + gcol] = f2bf(val);
        else
          ((float*)Cv)[(size_t)grow * ldc + coff + gcol] = val;
      }
    }
  }
}

// ---------------- chunked diagonal scan (gate fused into phase A) ----------------
// phase A: u = sigmoid(gz)*bx computed on the fly; local scans of CH steps
__global__ void k_scanA(const float* __restrict__ gz, const float* __restrict__ bx,
                        const float* __restrict__ Alog,
                        float* __restrict__ st, float* __restrict__ carry, int N) {
  int gid = blockIdx.x * 256 + threadIdx.x;
  if (gid >= Bdim * NCH * N) return;
  int n = gid % N;
  int c = (gid / N) % NCH;
  int b = gid / (N * NCH);
  float a = expf(Alog[n]);
  float s = 0.f;
  size_t base = ((size_t)b * Sd + (size_t)c * CH) * N + n;
  for (int t = 0; t < CH; ++t) {
    size_t idx = base + (size_t)t * N;
    float gv = 1.f / (1.f + expf(-gz[idx]));
    float uv = gv * bx[idx];
    s = a * s + uv;
    st[idx] = s;
  }
  carry[(b * NCH + c) * N + n] = s;
}

// phase B: exclusive scan of carries across chunks (tiny)
__global__ void k_scanB(const float* __restrict__ carry, const float* __restrict__ Alog,
                        float* __restrict__ cin, int N) {
  int i = blockIdx.x * 256 + threadIdx.x;
  if (i >= Bdim * N) return;
  int b = i / N, n = i % N;
  float aC = expf((float)CH * Alog[n]);
  float s = 0.f;
  for (int c = 0; c < NCH; ++c) {
    cin[(b * NCH + c) * N + n] = s;
    s = aC * s + carry[(b * NCH + c) * N + n];
  }
}

// phase C: states = local + A^(t+1)*carry_in, emit bf16
__global__ void k_scanC(const float* __restrict__ st, const float* __restrict__ cin,
                        const float* __restrict__ Alog, unsigned short* __restrict__ stbf, int N) {
  int gid = blockIdx.x * 256 + threadIdx.x;
  if (gid >= BSd * N) return;
  int n = gid % N;
  int row = gid / N;
  int b = row / Sd, sg = row % Sd;
  int c = sg / CH, t = sg % CH;
  float cv = cin[(b * NCH + c) * N + n];
  float val = st[gid] + expf((float)(t + 1) * Alog[n]) * cv;
  stbf[gid] = f2bf(val);
}

// ---------------- fused LN: z = LN(y + coef*emb)*g + be -> bf16 ----------------
__global__ void k_ln(const float* __restrict__ y, const float* __restrict__ emb,
                     const float* __restrict__ D, const float* __restrict__ g,
                     const float* __restrict__ be, unsigned short* __restrict__ out) {
  int row = blockIdx.x, t = threadIdx.x;
  f32x4 yv = *(const f32x4*)(y + (size_t)row * Hd + t * 4);
  f32x4 ev = *(const f32x4*)(emb + (size_t)row * Hd + t * 4);
  float vals[4];
  float sum = 0.f, sq = 0.f;
  #pragma unroll
  for (int j = 0; j < 4; ++j) {
    float coef = D ? (D[t * 4 + j] + 1.f) : 1.f;
    float v = yv[j] + coef * ev[j];
    vals[j] = v; sum += v; sq += v * v;
  }
  #pragma unroll
  for (int o = 32; o >= 1; o >>= 1) {
    sum += __shfl_xor(sum, o);
    sq += __shfl_xor(sq, o);
  }
  __shared__ float red[2][4];
  int w = t >> 6, lane = t & 63;
  if (lane == 0) { red[0][w] = sum; red[1][w] = sq; }
  __syncthreads();
  sum = red[0][0] + red[0][1] + red[0][2] + red[0][3];
  sq  = red[1][0] + red[1][1] + red[1][2] + red[1][3];
  float mean = sum * (1.f / Hd);
  float var = sq * (1.f / Hd) - mean * mean;
  float rs = rsqrtf(var + EPSf);
  us4 o4;
  #pragma unroll
  for (int j = 0; j < 4; ++j) {
    float z = (vals[j] - mean) * rs * g[t * 4 + j] + be[t * 4 + j];
    o4[j] = f2bf(z);
  }
  *(us4*)(out + (size_t)row * Hd + t * 4) = o4;
}

extern "C" void kernel_launch(void* const* d_in, const int* in_sizes, int n_in,
                              void* d_out, int out_size, void* d_ws, size_t ws_size,
                              hipStream_t stream) {
  (void)in_sizes; (void)n_in; (void)out_size; (void)ws_size;
  const int* x = (const int*)d_in[0];
  const float* E = (const float*)d_in[1];
  const float* Wf_ = (const float*)d_in[32];
  const float* bfb = (const float*)d_in[33];
  const float* gfp = (const float*)d_in[34];
  const float* bef = (const float*)d_in[35];
  const float* Wh_ = (const float*)d_in[36];
  const float* bh = (const float*)d_in[37];
  static const int sd[3] = {64, 128, 256};

  char* wsb = (char*)d_ws;
  size_t off = 0;
  auto alloc = [&](size_t bytes) -> void* {
    void* p = wsb + off;
    off += (bytes + 255) & ~(size_t)255;
    return p;
  };
  float* emb            = (float*)alloc((size_t)BSd * Hd * 4);
  unsigned short* embbf = (unsigned short*)alloc((size_t)BSd * Hd * 2);
  unsigned short* wgbf  = (unsigned short*)alloc((size_t)448 * Hd * 2);
  unsigned short* wbbf  = (unsigned short*)alloc((size_t)448 * Hd * 2);
  unsigned short* wcbf  = (unsigned short*)alloc((size_t)448 * Hd * 2);
  unsigned short* wobf  = (unsigned short*)alloc((size_t)3 * Hd * Hd * 2);
  unsigned short* wfbf  = (unsigned short*)alloc((size_t)3 * Hd * Hd * 2);
  unsigned short* whbf  = (unsigned short*)alloc((size_t)Vd * Hd * 2);
  float* gz             = (float*)alloc((size_t)BSd * 256 * 4);
  float* bx             = (float*)alloc((size_t)BSd * 256 * 4);
  float* stl            = (float*)alloc((size_t)BSd * 256 * 4);
  unsigned short* stbf  = (unsigned short*)alloc((size_t)BSd * 256 * 2);
  float* carry          = (float*)alloc((size_t)Bdim * NCH * 256 * 4);
  float* cin            = (float*)alloc((size_t)Bdim * NCH * 256 * 4);
  float* ybuf           = (float*)alloc((size_t)BSd * Hd * 4);
  unsigned short* zbf   = (unsigned short*)alloc((size_t)BSd * Hd * 2);
  unsigned short* combbf= (unsigned short*)alloc((size_t)BSd * 3 * Hd * 2);

  k_embed<<<BSd, 256, 0, stream>>>(x, E, emb, embbf);

  const int owg[3] = {0, 64 * Hd, 192 * Hd};
  for (int i = 0; i < 3; ++i) {
    int n4 = sd[i] * Hd / 4;
    k_cvt<<<(n4 + 255) / 256, 256, 0, stream>>>((const float*)d_in[2 + 10 * i + 4], wgbf + owg[i], n4);
    k_cvt<<<(n4 + 255) / 256, 256, 0, stream>>>((const float*)d_in[2 + 10 * i + 1], wbbf + owg[i], n4);
    k_cvt<<<(n4 + 255) / 256, 256, 0, stream>>>((const float*)d_in[2 + 10 * i + 2], wcbf + owg[i], n4);
    int m4 = Hd * Hd / 4;
    k_cvt<<<(m4 + 255) / 256, 256, 0, stream>>>((const float*)d_in[2 + 10 * i + 6], wobf + (size_t)i * Hd * Hd, m4);
  }
  {
    int n4 = 3 * Hd * Hd / 4;
    k_cvt<<<(n4 + 255) / 256, 256, 0, stream>>>(Wf_, wfbf, n4);
  }
  {
    int n4 = Vd * Hd / 4;
    k_cvt<<<(n4 + 255) / 256, 256, 0, stream>>>(Wh_, whbf, n4);
  }

  const int TM = BSd / 128;  // 32 M-tiles
  for (int i = 0; i < 3; ++i) {
    int N = sd[i];
    const float* Alog = (const float*)d_in[2 + 10 * i + 0];
    const float* Dv   = (const float*)d_in[2 + 10 * i + 3];
    const float* bg   = (const float*)d_in[2 + 10 * i + 5];
    const float* bo   = (const float*)d_in[2 + 10 * i + 7];
    const float* gg   = (const float*)d_in[2 + 10 * i + 8];
    const float* be   = (const float*)d_in[2 + 10 * i + 9];

    int tn = (N + 127) / 128;
    gemm_nt<0><<<tn * TM, 256, 0, stream>>>(embbf, wgbf + owg[i], bg, gz, N, Hd, N, 0, TM);
    gemm_nt<0><<<tn * TM, 256, 0, stream>>>(embbf, wbbf + owg[i], nullptr, bx, N, Hd, N, 0, TM);

    int totA = Bdim * NCH * N;
    k_scanA<<<(totA + 255) / 256, 256, 0, stream>>>(gz, bx, Alog, stl, carry, N);
    k_scanB<<<(Bdim * N + 255) / 256, 256, 0, stream>>>(carry, Alog, cin, N);
    int totC = BSd * N;
    k_scanC<<<(totC + 255) / 256, 256, 0, stream>>>(stl, cin, Alog, stbf, N);

    gemm_nt<0><<<(Hd / 128) * TM, 256, 0, stream>>>(stbf, wcbf + owg[i], nullptr, ybuf, Hd, N, Hd, 0, TM);
    k_ln<<<BSd, 256, 0, stream>>>(ybuf, emb, Dv, gg, be, zbf);
    gemm_nt<1><<<(Hd / 128) * TM, 256, 0, stream>>>(zbf, wobf + (size_t)i * Hd * Hd, bo, combbf, Hd, Hd, 3 * Hd, i * Hd, TM);
  }

  gemm_nt<0><<<(Hd / 128) * TM, 256, 0, stream>>>(combbf, wfbf, bfb, ybuf, Hd, 3 * Hd, Hd, 0, TM);
  k_ln<<<BSd, 256, 0, stream>>>(ybuf, emb, nullptr, gfp, bef, zbf);

  gemm_nt<0><<<(Vd / 128) * TM, 256, 0, stream>>>(zbf, whbf, bh, (float*)d_out, Vd, Hd, Vd, 0, TM);
}

// Round 4
// 826.863 us; speedup vs baseline: 1.4267x; 1.3446x over previous
//
#include <hip/hip_runtime.h>
#include <hip/hip_bf16.h>

#define Hd 1024
#define Bdim 2
#define Sd 2048
#define BSd 4096
#define Vd 32000
#define EPSf 1e-5f
#define CH 16
#define NCH 128

typedef __attribute__((ext_vector_type(8))) short short8;
typedef __attribute__((ext_vector_type(4))) float f32x4;
typedef __attribute__((ext_vector_type(4))) unsigned short us4;

__device__ __forceinline__ unsigned short f2bf(float f) {
  union { float f; unsigned int u; } v; v.f = f;
  return (unsigned short)((v.u + 0x7fffu + ((v.u >> 16) & 1u)) >> 16);
}

typedef __attribute__((address_space(1))) const void gvoid_t;
typedef __attribute__((address_space(3))) void svoid_t;
__device__ __forceinline__ void gl_lds16(const void* g, void* s) {
  __builtin_amdgcn_global_load_lds((gvoid_t*)g, (svoid_t*)s, 16, 0, 0);
}

// ---------------- convert fp32 -> bf16 (vectorized x4) ----------------
__global__ void k_cvt(const float* __restrict__ in, unsigned short* __restrict__ out, int n4) {
  int i = blockIdx.x * 256 + threadIdx.x;
  if (i >= n4) return;
  f32x4 v = *(const f32x4*)(in + (size_t)i * 4);
  us4 o;
  o[0] = f2bf(v[0]); o[1] = f2bf(v[1]); o[2] = f2bf(v[2]); o[3] = f2bf(v[3]);
  *(us4*)(out + (size_t)i * 4) = o;
}

// ---------------- embedding gather -> fp32 + bf16 ----------------
__global__ void k_embed(const int* __restrict__ x, const float* __restrict__ E,
                        float* __restrict__ emb, unsigned short* __restrict__ embbf) {
  int row = blockIdx.x, t = threadIdx.x;
  int id = x[row];
  f32x4 v = *(const f32x4*)(E + (size_t)id * Hd + t * 4);
  *(f32x4*)(emb + (size_t)row * Hd + t * 4) = v;
  us4 o;
  o[0] = f2bf(v[0]); o[1] = f2bf(v[1]); o[2] = f2bf(v[2]); o[3] = f2bf(v[3]);
  *(us4*)(embbf + (size_t)row * Hd + t * 4) = o;
}

// ---------------- bf16 NT GEMM, 2-phase double-buffered ----------------
// C[M,N] = A[M,K]*B[N,K]^T (+bias). BK=64. global_load_lds width-16 staging,
// LINEAR LDS dest + pre-swizzled global source (col16 ^= row&7) + same XOR on
// ds_read (rule #21 both-sides T2) -> no 16-way start-bank conflicts.
// Pipeline (T3 minimum, race-free): stage(next buf) BEFORE compute(cur buf),
// ONE __syncthreads (vmcnt0+lgkmcnt0+barrier) per K-step.
// 1-D grid, bijective XCD remap, N-panel-major (B panel L2-hot).
template<int BM, int BN, int WM, int WN, int BF16_OUT>
__launch_bounds__(WM * WN * 64)
__global__ void gemm2ph(const unsigned short* __restrict__ A,
                        const unsigned short* __restrict__ Bw,
                        const float* __restrict__ bias,
                        void* __restrict__ Cv,
                        int N, int K, int ldc, int coff, int tm)
{
  constexpr int NT = WM * WN * 64;
  constexpr int MF = BM / WM / 16;
  constexpr int NF = BN / WN / 16;
  constexpr int ASZ = BM * 64;   // elems per A buffer
  constexpr int BSZ = BN * 64;
  constexpr int AR = (ASZ * 2) / (NT * 16);  // staging rounds
  constexpr int BR = (BSZ * 2) / (NT * 16);
  __shared__ __align__(16) unsigned short Sm[2 * (ASZ + BSZ)];

  int T = gridDim.x;
  int orig = blockIdx.x;
  int q = T >> 3, r = T & 7;
  int xc = orig & 7, sdv = orig >> 3;
  int wgid = (xc < r ? xc * (q + 1) : r * (q + 1) + (xc - r) * q) + sdv;
  int n_t = wgid / tm, m_t = wgid % tm;
  int row0 = m_t * BM, col0 = n_t * BN;

  int tid = threadIdx.x;
  int wave = tid >> 6, lane = tid & 63;
  int wm = wave / WN, wn = wave % WN;
  int wr = wm * (BM / WM), wc = wn * (BN / WN);
  int lr = lane & 15;
  int klane = lane >> 4;  // 0..3 -> 16B col slot within 64-elem row

  f32x4 acc[MF][NF] = {};

  auto stage = [&](int buf, int k0) {
    unsigned short* Ab = Sm + buf * (ASZ + BSZ);
    unsigned short* Bb = Ab + ASZ;
    #pragma unroll
    for (int j = 0; j < AR; ++j) {
      int slot = j * NT + tid;
      int lrow = slot >> 3, c16 = slot & 7;
      int scol = (c16 ^ (lrow & 7)) * 8;  // pre-swizzled source col (elems)
      gl_lds16(A + (size_t)(row0 + lrow) * K + k0 + scol, Ab + (j * NT + wave * 64) * 8);
    }
    #pragma unroll
    for (int j = 0; j < BR; ++j) {
      int slot = j * NT + tid;
      int lrow = slot >> 3, c16 = slot & 7;
      int scol = (c16 ^ (lrow & 7)) * 8;
      int brow = col0 + lrow;
      if (brow >= N) brow = N - 1;  // clamp (results masked at store)
      gl_lds16(Bw + (size_t)brow * K + k0 + scol, Bb + (j * NT + wave * 64) * 8);
    }
  };

  auto compute = [&](int buf) {
    const unsigned short* Ab = Sm + buf * (ASZ + BSZ);
    const unsigned short* Bb = Ab + ASZ;
    #pragma unroll
    for (int kk = 0; kk < 2; ++kk) {
      short8 afr[MF], bfr[NF];
      #pragma unroll
      for (int m = 0; m < MF; ++m) {
        int row = wr + m * 16 + lr;
        int cs = (kk * 4 + klane) ^ (row & 7);
        afr[m] = *(const short8*)(Ab + row * 64 + cs * 8);
      }
      #pragma unroll
      for (int n = 0; n < NF; ++n) {
        int row = wc + n * 16 + lr;
        int cs = (kk * 4 + klane) ^ (row & 7);
        bfr[n] = *(const short8*)(Bb + row * 64 + cs * 8);
      }
      #pragma unroll
      for (int m = 0; m < MF; ++m)
        #pragma unroll
        for (int n = 0; n < NF; ++n)
          acc[m][n] = __builtin_amdgcn_mfma_f32_16x16x32_bf16(afr[m], bfr[n], acc[m][n], 0, 0, 0);
    }
  };

  int nt = K >> 6;
  stage(0, 0);
  __syncthreads();
  for (int t = 0; t < nt - 1; ++t) {
    stage((t & 1) ^ 1, (t + 1) * 64);  // prefetch next tile (other buffer)
    compute(t & 1);                     // MFMA on current tile
    __syncthreads();                    // drains vmcnt (stage had whole compute to land)
  }
  compute((nt - 1) & 1);

  int rb = (lane >> 4) * 4;
  #pragma unroll
  for (int m = 0; m < MF; ++m) {
    #pragma unroll
    for (int n = 0; n < NF; ++n) {
      int gcol = col0 + wc + n * 16 + lr;
      if (gcol >= N) continue;
      float bv = bias ? bias[gcol] : 0.f;
      #pragma unroll
      for (int j = 0; j < 4; ++j) {
        int grow = row0 + wr + m * 16 + rb + j;
        float val = acc[m][n][j] + bv;
        if (BF16_OUT)
          ((unsigned short*)Cv)[(size_t)grow * ldc + coff + gcol] = f2bf(val);
        else
          ((float*)Cv)[(size_t)grow * ldc + coff + gcol] = val;
      }
    }
  }
}

// ---------------- chunked diagonal scan (gate fused into phase A) ----------------
__global__ void k_scanA(const float* __restrict__ gz, const float* __restrict__ bx,
                        const float* __restrict__ Alog,
                        float* __restrict__ st, float* __restrict__ carry, int N) {
  int gid = blockIdx.x * 256 + threadIdx.x;
  if (gid >= Bdim * NCH * N) return;
  int n = gid % N;
  int c = (gid / N) % NCH;
  int b = gid / (N * NCH);
  float a = expf(Alog[n]);
  float s = 0.f;
  size_t base = ((size_t)b * Sd + (size_t)c * CH) * N + n;
  for (int t = 0; t < CH; ++t) {
    size_t idx = base + (size_t)t * N;
    float gv = 1.f / (1.f + expf(-gz[idx]));
    float uv = gv * bx[idx];
    s = a * s + uv;
    st[idx] = s;
  }
  carry[(b * NCH + c) * N + n] = s;
}

__global__ void k_scanB(const float* __restrict__ carry, const float* __restrict__ Alog,
                        float* __restrict__ cin, int N) {
  int i = blockIdx.x * 256 + threadIdx.x;
  if (i >= Bdim * N) return;
  int b = i / N, n = i % N;
  float aC = expf((float)CH * Alog[n]);
  float s = 0.f;
  for (int c = 0; c < NCH; ++c) {
    cin[(b * NCH + c) * N + n] = s;
    s = aC * s + carry[(b * NCH + c) * N + n];
  }
}

__global__ void k_scanC(const float* __restrict__ st, const float* __restrict__ cin,
                        const float* __restrict__ Alog, unsigned short* __restrict__ stbf, int N) {
  int gid = blockIdx.x * 256 + threadIdx.x;
  if (gid >= BSd * N) return;
  int n = gid % N;
  int row = gid / N;
  int b = row / Sd, sg = row % Sd;
  int c = sg / CH, t = sg % CH;
  float cv = cin[(b * NCH + c) * N + n];
  float val = st[gid] + expf((float)(t + 1) * Alog[n]) * cv;
  stbf[gid] = f2bf(val);
}

// ---------------- fused LN: z = LN(y + coef*emb)*g + be -> bf16 ----------------
__global__ void k_ln(const float* __restrict__ y, const float* __restrict__ emb,
                     const float* __restrict__ D, const float* __restrict__ g,
                     const float* __restrict__ be, unsigned short* __restrict__ out) {
  int row = blockIdx.x, t = threadIdx.x;
  f32x4 yv = *(const f32x4*)(y + (size_t)row * Hd + t * 4);
  f32x4 ev = *(const f32x4*)(emb + (size_t)row * Hd + t * 4);
  float vals[4];
  float sum = 0.f, sq = 0.f;
  #pragma unroll
  for (int j = 0; j < 4; ++j) {
    float coef = D ? (D[t * 4 + j] + 1.f) : 1.f;
    float v = yv[j] + coef * ev[j];
    vals[j] = v; sum += v; sq += v * v;
  }
  #pragma unroll
  for (int o = 32; o >= 1; o >>= 1) {
    sum += __shfl_xor(sum, o);
    sq += __shfl_xor(sq, o);
  }
  __shared__ float red[2][4];
  int w = t >> 6, lane = t & 63;
  if (lane == 0) { red[0][w] = sum; red[1][w] = sq; }
  __syncthreads();
  sum = red[0][0] + red[0][1] + red[0][2] + red[0][3];
  sq  = red[1][0] + red[1][1] + red[1][2] + red[1][3];
  float mean = sum * (1.f / Hd);
  float var = sq * (1.f / Hd) - mean * mean;
  float rs = rsqrtf(var + EPSf);
  us4 o4;
  #pragma unroll
  for (int j = 0; j < 4; ++j) {
    float z = (vals[j] - mean) * rs * g[t * 4 + j] + be[t * 4 + j];
    o4[j] = f2bf(z);
  }
  *(us4*)(out + (size_t)row * Hd + t * 4) = o4;
}

extern "C" void kernel_launch(void* const* d_in, const int* in_sizes, int n_in,
                              void* d_out, int out_size, void* d_ws, size_t ws_size,
                              hipStream_t stream) {
  (void)in_sizes; (void)n_in; (void)out_size; (void)ws_size;
  const int* x = (const int*)d_in[0];
  const float* E = (const float*)d_in[1];
  const float* Wf_ = (const float*)d_in[32];
  const float* bfb = (const float*)d_in[33];
  const float* gfp = (const float*)d_in[34];
  const float* bef = (const float*)d_in[35];
  const float* Wh_ = (const float*)d_in[36];
  const float* bh = (const float*)d_in[37];
  static const int sd[3] = {64, 128, 256};

  char* wsb = (char*)d_ws;
  size_t off = 0;
  auto alloc = [&](size_t bytes) -> void* {
    void* p = wsb + off;
    off += (bytes + 255) & ~(size_t)255;
    return p;
  };
  float* emb            = (float*)alloc((size_t)BSd * Hd * 4);
  unsigned short* embbf = (unsigned short*)alloc((size_t)BSd * Hd * 2);
  unsigned short* wgbf  = (unsigned short*)alloc((size_t)448 * Hd * 2);
  unsigned short* wbbf  = (unsigned short*)alloc((size_t)448 * Hd * 2);
  unsigned short* wcbf  = (unsigned short*)alloc((size_t)448 * Hd * 2);
  unsigned short* wobf  = (unsigned short*)alloc((size_t)3 * Hd * Hd * 2);
  unsigned short* wfbf  = (unsigned short*)alloc((size_t)3 * Hd * Hd * 2);
  unsigned short* whbf  = (unsigned short*)alloc((size_t)Vd * Hd * 2);
  float* gz             = (float*)alloc((size_t)BSd * 256 * 4);
  float* bx             = (float*)alloc((size_t)BSd * 256 * 4);
  float* stl            = (float*)alloc((size_t)BSd * 256 * 4);
  unsigned short* stbf  = (unsigned short*)alloc((size_t)BSd * 256 * 2);
  float* carry          = (float*)alloc((size_t)Bdim * NCH * 256 * 4);
  float* cin            = (float*)alloc((size_t)Bdim * NCH * 256 * 4);
  float* ybuf           = (float*)alloc((size_t)BSd * Hd * 4);
  unsigned short* zbf   = (unsigned short*)alloc((size_t)BSd * Hd * 2);
  unsigned short* combbf= (unsigned short*)alloc((size_t)BSd * 3 * Hd * 2);

  k_embed<<<BSd, 256, 0, stream>>>(x, E, emb, embbf);

  const int owg[3] = {0, 64 * Hd, 192 * Hd};
  for (int i = 0; i < 3; ++i) {
    int n4 = sd[i] * Hd / 4;
    k_cvt<<<(n4 + 255) / 256, 256, 0, stream>>>((const float*)d_in[2 + 10 * i + 4], wgbf + owg[i], n4);
    k_cvt<<<(n4 + 255) / 256, 256, 0, stream>>>((const float*)d_in[2 + 10 * i + 1], wbbf + owg[i], n4);
    k_cvt<<<(n4 + 255) / 256, 256, 0, stream>>>((const float*)d_in[2 + 10 * i + 2], wcbf + owg[i], n4);
    int m4 = Hd * Hd / 4;
    k_cvt<<<(m4 + 255) / 256, 256, 0, stream>>>((const float*)d_in[2 + 10 * i + 6], wobf + (size_t)i * Hd * Hd, m4);
  }
  {
    int n4 = 3 * Hd * Hd / 4;
    k_cvt<<<(n4 + 255) / 256, 256, 0, stream>>>(Wf_, wfbf, n4);
  }
  {
    int n4 = Vd * Hd / 4;
    k_cvt<<<(n4 + 255) / 256, 256, 0, stream>>>(Wh_, whbf, n4);
  }

  const int TM = BSd / 128;  // 32 M-tiles for 128-row tiles
  for (int i = 0; i < 3; ++i) {
    int N = sd[i];
    const float* Alog = (const float*)d_in[2 + 10 * i + 0];
    const float* Dv   = (const float*)d_in[2 + 10 * i + 3];
    const float* bg   = (const float*)d_in[2 + 10 * i + 5];
    const float* bo   = (const float*)d_in[2 + 10 * i + 7];
    const float* gg   = (const float*)d_in[2 + 10 * i + 8];
    const float* be   = (const float*)d_in[2 + 10 * i + 9];

    int tn = (N + 127) / 128;
    gemm2ph<128,128,2,2,0><<<tn * TM, 256, 0, stream>>>(embbf, wgbf + owg[i], bg, gz, N, Hd, N, 0, TM);
    gemm2ph<128,128,2,2,0><<<tn * TM, 256, 0, stream>>>(embbf, wbbf + owg[i], nullptr, bx, N, Hd, N, 0, TM);

    int totA = Bdim * NCH * N;
    k_scanA<<<(totA + 255) / 256, 256, 0, stream>>>(gz, bx, Alog, stl, carry, N);
    k_scanB<<<(Bdim * N + 255) / 256, 256, 0, stream>>>(carry, Alog, cin, N);
    int totC = BSd * N;
    k_scanC<<<(totC + 255) / 256, 256, 0, stream>>>(stl, cin, Alog, stbf, N);

    gemm2ph<128,128,2,2,0><<<(Hd / 128) * TM, 256, 0, stream>>>(stbf, wcbf + owg[i], nullptr, ybuf, Hd, N, Hd, 0, TM);
    k_ln<<<BSd, 256, 0, stream>>>(ybuf, emb, Dv, gg, be, zbf);
    gemm2ph<128,128,2,2,1><<<(Hd / 128) * TM, 256, 0, stream>>>(zbf, wobf + (size_t)i * Hd * Hd, bo, combbf, Hd, Hd, 3 * Hd, i * Hd, TM);
  }

  gemm2ph<128,128,2,2,0><<<(Hd / 128) * TM, 256, 0, stream>>>(combbf, wfbf, bfb, ybuf, Hd, 3 * Hd, Hd, 0, TM);
  k_ln<<<BSd, 256, 0, stream>>>(ybuf, emb, nullptr, gfp, bef, zbf);

  // logits: 256x256 tile, 8 waves, 2000 blocks
  const int TM256 = BSd / 256;  // 16
  gemm2ph<256,256,2,4,0><<<(Vd / 256) * TM256, 512, 0, stream>>>(zbf, whbf, bh, (float*)d_out, Vd, Hd, Vd, 0, TM256);
}